// Round 7
// baseline (222.431 us; speedup 1.0000x reference)
//
#include <hip/hip_runtime.h>
#include <hip/hip_bf16.h>
#include <stdint.h>

#define B_ 4
#define S_ 1024
#define E_ 8
#define DE_ 128
#define SCALE_ 0.03125f   // 1/sqrt(1024)

typedef __attribute__((ext_vector_type(8))) short short8;
typedef __attribute__((ext_vector_type(4))) float f32x4;
typedef unsigned short ushort_t;
typedef unsigned int uint32;
typedef unsigned long long u64;
typedef unsigned char uchar;

__device__ __forceinline__ ushort_t f2bf(float f) {
    uint32 u = __float_as_uint(f);
    uint32 r = u + 0x7fffu + ((u >> 16) & 1u);
    return (ushort_t)(r >> 16);
}
__device__ __forceinline__ float bf2f(ushort_t us) {
    return __uint_as_float(((uint32)us) << 16);
}

// fp32 -> fp8 e4m3fn, RNE, saturating. Manual (no header dependency).
__device__ __forceinline__ uchar f2fp8(float f) {
    float a = fminf(fmaxf(f, -448.f), 448.f);
    uint32 u = __float_as_uint(a);
    uint32 s = (u >> 31) << 7;
    int ex = (int)((u >> 23) & 0xff);
    uint32 man = u & 0x7fffff;
    int e8 = ex - 127 + 7;
    if (e8 >= 1) {
        uint32 m = man >> 20;
        uint32 rem = man & 0xfffff;
        if (rem > 0x80000u || (rem == 0x80000u && (m & 1))) ++m;
        if (m == 8) { m = 0; ++e8; }
        if (e8 > 15) { e8 = 15; m = 6; }          // saturate to 448
        return (uchar)(s | ((uint32)e8 << 3) | m);
    } else {
        int m = (int)rintf(fabsf(a) * 512.f);     // subnormal units 2^-9
        if (m > 7) m = 7;
        return (uchar)(s | (uint32)m);
    }
}

__device__ __forceinline__ void top2(const float* rp, int& i1, int& i2) {
    float v1 = rp[0]; i1 = 0;
    #pragma unroll
    for (int i = 1; i < 8; ++i) { float v = rp[i]; if (v > v1) { v1 = v; i1 = i; } }
    float v2 = -1e30f; i2 = 0;
    #pragma unroll
    for (int i = 0; i < 8; ++i) {
        if (i == i1) continue;
        float v = rp[i]; if (v > v2) { v2 = v; i2 = i; }
    }
}

// ---------------------------------------------------------------------------
// Kernel 1: prep (unchanged, ~13 us ≈ HBM floor). Q,K fp32 -> fp8 planes;
// V -> bf16 transposed Vt (top-2 planes); zero-fill non-top2 out slices.
// ---------------------------------------------------------------------------
__global__ __launch_bounds__(256) void prep_kernel(
        const float* __restrict__ Q, const float* __restrict__ K,
        const float* __restrict__ V, const float* __restrict__ route,
        const int* __restrict__ em,
        uchar* __restrict__ Qb, uchar* __restrict__ Kb,
        ushort_t* __restrict__ Vt, float* __restrict__ out) {
    __shared__ ushort_t tile[64][130];
    const int tid = threadIdx.x;
    const int sc = blockIdx.x, e = blockIdx.y, b = blockIdx.z;
    const int s0 = sc * 64;
    const size_t plane8 = ((size_t)(b * 8 + e)) << 17;   // bytes (fp8)

    const bool ak = em[e * B_ + b] != 0;
    int i1, i2; top2(route + b * 8, i1, i2);
    const bool av = (e == i1) || (e == i2);

    if (!av) {
        #pragma unroll
        for (int i = 0; i < 8; ++i) {
            int idx = tid + i * 256, r = idx >> 5, c4 = idx & 31;
            *(float4*)(out + (((size_t)(b * 1024 + s0 + r)) << 10) + (e << 7) + (c4 << 2))
                = make_float4(0.f, 0.f, 0.f, 0.f);
        }
    }
    if (ak) {
        #pragma unroll
        for (int i = 0; i < 2; ++i) {
            int u = tid + i * 256;              // 0..511: 16-elem groups
            int r = u >> 3, dg = u & 7;
            const float* qs = Q + ((size_t)(b * 1024 + s0 + r) << 10) + (e << 7) + (dg << 4);
            const float* ks = K + ((size_t)(b * 1024 + s0 + r) << 10) + (e << 7) + (dg << 4);
            union { uint4 w; uchar c[16]; } oq, ok;
            #pragma unroll
            for (int j = 0; j < 4; ++j) {
                float4 qv = ((const float4*)qs)[j];
                float4 kv = ((const float4*)ks)[j];
                oq.c[j*4+0] = f2fp8(qv.x); oq.c[j*4+1] = f2fp8(qv.y);
                oq.c[j*4+2] = f2fp8(qv.z); oq.c[j*4+3] = f2fp8(qv.w);
                ok.c[j*4+0] = f2fp8(kv.x); ok.c[j*4+1] = f2fp8(kv.y);
                ok.c[j*4+2] = f2fp8(kv.z); ok.c[j*4+3] = f2fp8(kv.w);
            }
            size_t oo = plane8 + ((size_t)(s0 + r) << 7) + (dg << 4);
            *(uint4*)(Qb + oo) = oq.w;
            *(uint4*)(Kb + oo) = ok.w;
        }
    }
    if (av) {
        #pragma unroll
        for (int i = 0; i < 8; ++i) {
            int idx = tid + i * 256, r = idx >> 5, c4 = idx & 31;
            size_t in_off = ((size_t)(b * 1024 + s0 + r) << 10) + (e << 7) + (c4 << 2);
            float4 v = *(const float4*)(V + in_off);
            ushort_t* p = &tile[r][c4 << 2];
            p[0] = f2bf(v.x); p[1] = f2bf(v.y); p[2] = f2bf(v.z); p[3] = f2bf(v.w);
        }
        __syncthreads();
        #pragma unroll
        for (int i = 0; i < 4; ++i) {
            int item = tid + i * 256, d = item & 127, sg = item >> 7;
            union { uint4 q; ushort_t u[8]; } tmp;
            #pragma unroll
            for (int j = 0; j < 8; ++j) tmp.u[j] = tile[sg * 8 + j][d];
            *(uint4*)(Vt + (((size_t)(b * 8 + e)) << 17) + (((size_t)d) << 10)
                      + s0 + (sg << 3)) = tmp.q;
        }
    }
}

// ---------------------------------------------------------------------------
// Kernel 2a: qk_kernel (R7). One block per (16-row strip, batch, expert).
// Grid 2048, 256 thr (4 waves): up to 8 blocks/CU, 16+ waves of independent
// barrier-free work — the TLP the mega-kernel never had (R6 post-mortem:
// all utilizations <7%, 1 lockstep block/CU was the floor).
// Wave w covers t in [w*256, w*256+256). Writes per-expert p strip (bf16)
// and per-row sums to workspace. XCD decode pins batch b to XCD pair.
// ---------------------------------------------------------------------------
__global__ __launch_bounds__(256) void qk_kernel(
        const uchar* __restrict__ Qb, const uchar* __restrict__ Kb,
        const int* __restrict__ em,
        ushort_t* __restrict__ pWS, float* __restrict__ rsumWS) {
    __shared__ float red[4][16];

    const int p = blockIdx.x;
    const int xcd = p & 7, b = xcd >> 1;
    const int u = p >> 3;
    const int e = u & 7;
    const int stile = ((u >> 3) & 31) + ((xcd & 1) << 5);
    if (em[e * B_ + b] == 0) return;

    const int s0 = stile * 16;
    const int tid = threadIdx.x;
    const int w = tid >> 6, lane = tid & 63;
    const int quad = lane >> 4, l16 = lane & 15;

    const uchar* kp = Kb + (((size_t)(b * 8 + e)) << 17);
    const uchar* qp = Qb + (((size_t)(b * 8 + e)) << 17) + ((size_t)s0 << 7)
                      + l16 * 128 + quad * 8;
    u64 af[4];
    #pragma unroll
    for (int kk = 0; kk < 4; ++kk) af[kk] = *(const u64*)(qp + kk * 32);

    ushort_t* pout = pWS + (((size_t)((b * 8 + e) * 64 + stile)) << 14); // 16x1024
    float rsum[4] = {0.f, 0.f, 0.f, 0.f};

    #pragma unroll
    for (int nt = 0; nt < 16; ++nt) {
        int trow = w * 256 + nt * 16 + l16;
        const uchar* krow = kp + (size_t)trow * 128 + quad * 8;
        u64 b0 = *(const u64*)(krow);
        u64 b1 = *(const u64*)(krow + 32);
        u64 b2 = *(const u64*)(krow + 64);
        u64 b3 = *(const u64*)(krow + 96);
        f32x4 s = {0.f, 0.f, 0.f, 0.f};
        s = __builtin_amdgcn_mfma_f32_16x16x32_fp8_fp8((long)af[0], (long)b0, s, 0, 0, 0);
        s = __builtin_amdgcn_mfma_f32_16x16x32_fp8_fp8((long)af[1], (long)b1, s, 0, 0, 0);
        s = __builtin_amdgcn_mfma_f32_16x16x32_fp8_fp8((long)af[2], (long)b2, s, 0, 0, 0);
        s = __builtin_amdgcn_mfma_f32_16x16x32_fp8_fp8((long)af[3], (long)b3, s, 0, 0, 0);
        #pragma unroll
        for (int r = 0; r < 4; ++r) {
            float pv = __expf(s[r] * SCALE_);
            rsum[r] += pv;
            pout[(quad * 4 + r) * 1024 + trow] = f2bf(pv);
        }
    }

    // row-sum over this wave's 256 t (reduce across the 16 t-lanes)
    #pragma unroll
    for (int off = 1; off < 16; off <<= 1)
        #pragma unroll
        for (int r = 0; r < 4; ++r) rsum[r] += __shfl_xor(rsum[r], off, 64);
    if (l16 == 0) {
        #pragma unroll
        for (int r = 0; r < 4; ++r) red[w][quad * 4 + r] = rsum[r];
    }
    __syncthreads();
    if (tid < 16) {
        float l = red[0][tid] + red[1][tid] + red[2][tid] + red[3][tid];
        rsumWS[((b * 8 + e) * 64 + stile) * 16 + tid] = l;
    }
}

// ---------------------------------------------------------------------------
// Kernel 2b: pv_kernel (R7). One block per (16-row strip, batch, sel expert).
// Grid 512, 256 thr. Combines attn = sum_e p_e * rinv_e in f32 per A-frag,
// then PV via bf16 MFMA. No barriers after the tiny rinv stage. Both sels of
// a stile land on the same XCD (p-strip L2 reuse).
// Wave w owns d in {w*16..+15} u {64+w*16..+15}.
// ---------------------------------------------------------------------------
__global__ __launch_bounds__(256) void pv_kernel(
        const ushort_t* __restrict__ pWS, const float* __restrict__ rsumWS,
        const ushort_t* __restrict__ Vt, const float* __restrict__ route,
        const int* __restrict__ em, float* __restrict__ out) {
    __shared__ float rinvL[8][16];

    const int p = blockIdx.x;
    const int xcd = p & 7, b = xcd >> 1;
    const int idx = (p >> 3) + ((xcd & 1) << 6);   // 0..127
    const int stile = idx >> 1, sel = idx & 1;
    const int s0 = stile * 16;
    const int tid = threadIdx.x;
    const int w = tid >> 6, lane = tid & 63;
    const int quad = lane >> 4, l16 = lane & 15;

    uint32 epack = 0; int ne = 0;
    #pragma unroll
    for (int e = 0; e < 8; ++e)
        if (em[e * B_ + b] != 0) { epack |= (uint32)e << (3 * ne); ++ne; }
    int i1, i2; top2(route + b * 8, i1, i2);
    const int eSel = sel ? i2 : i1;

    if (tid < ne * 16) {
        int i = tid >> 4, row = tid & 15;
        int e = (epack >> (3 * i)) & 7;
        rinvL[i][row] = 1.0f / rsumWS[((b * 8 + e) * 64 + stile) * 16 + row];
    }
    __syncthreads();

    const uchar* vp = (const uchar*)(Vt + (((size_t)(b * 8 + eSel)) << 17));
    const uchar* v0 = vp + (size_t)(w * 16 + l16) * 2048 + quad * 16;
    const uchar* v1 = vp + (size_t)(64 + w * 16 + l16) * 2048 + quad * 16;
    const size_t pbase = (((size_t)(b * 8)) * 64 + stile) << 14;

    f32x4 oa0 = {0.f, 0.f, 0.f, 0.f};
    f32x4 oa1 = {0.f, 0.f, 0.f, 0.f};

    #pragma unroll 4
    for (int tt = 0; tt < 32; ++tt) {
        float aj[8] = {0.f, 0.f, 0.f, 0.f, 0.f, 0.f, 0.f, 0.f};
        for (int i = 0; i < ne; ++i) {
            int e = (epack >> (3 * i)) & 7;
            const ushort_t* ps = pWS + pbase + (((size_t)e * 64) << 14)
                                 + l16 * 1024 + tt * 32 + quad * 8;
            short8 pv = *(const short8*)ps;
            float ri = rinvL[i][l16];
            #pragma unroll
            for (int j = 0; j < 8; ++j)
                aj[j] = fmaf(bf2f((ushort_t)pv[j]), ri, aj[j]);
        }
        short8 afr;
        #pragma unroll
        for (int j = 0; j < 8; ++j) afr[j] = (short)f2bf(aj[j]);
        short8 bf0 = *(const short8*)(v0 + tt * 64);
        short8 bf1 = *(const short8*)(v1 + tt * 64);
        oa0 = __builtin_amdgcn_mfma_f32_16x16x32_bf16(afr, bf0, oa0, 0, 0, 0);
        oa1 = __builtin_amdgcn_mfma_f32_16x16x32_bf16(afr, bf1, oa1, 0, 0, 0);
    }
    #pragma unroll
    for (int r = 0; r < 4; ++r)
        out[(((size_t)(b * 1024 + s0 + quad * 4 + r)) << 10)
            + eSel * 128 + w * 16 + l16] = oa0[r];
    #pragma unroll
    for (int r = 0; r < 4; ++r)
        out[(((size_t)(b * 1024 + s0 + quad * 4 + r)) << 10)
            + eSel * 128 + 64 + w * 16 + l16] = oa1[r];
}

// ---------------------------------------------------------------------------
extern "C" void kernel_launch(void* const* d_in, const int* in_sizes, int n_in,
                              void* d_out, int out_size, void* d_ws, size_t ws_size,
                              hipStream_t stream) {
    const float* Q     = (const float*)d_in[0];
    const float* K     = (const float*)d_in[1];
    const float* V     = (const float*)d_in[2];
    const float* route = (const float*)d_in[3];
    const int*   em    = (const int*)d_in[4];
    float* out = (float*)d_out;

    const size_t NB = (size_t)B_ * E_ * S_ * DE_;     // 4.19M elems
    uchar* base = (uchar*)d_ws;
    uchar* Qb = base;                                  // fp8 (NB bytes)
    uchar* Kb = Qb + NB;                               // fp8 (NB bytes)
    ushort_t* Vt = (ushort_t*)(Kb + NB);               // bf16 (NB elems = 8MB)
    ushort_t* pWS = (ushort_t*)(base + 4 * NB);        // [B][E][64][16][1024] bf16 = 64MB
    float* rsumWS = (float*)(base + 4 * NB + ((size_t)B_ * E_ * S_ * S_ * 2)); // 128KB

    dim3 gp(16, 8, 4);
    prep_kernel<<<gp, 256, 0, stream>>>(Q, K, V, route, em, Qb, Kb, Vt, out);
    qk_kernel<<<dim3(2048), 256, 0, stream>>>(Qb, Kb, em, pWS, rsumWS);
    pv_kernel<<<dim3(512), 256, 0, stream>>>(pWS, rsumWS, Vt, route, em, out);
}

// Round 9
// 129.235 us; speedup vs baseline: 1.7211x; 1.7211x over previous
//
#include <hip/hip_runtime.h>
#include <hip/hip_bf16.h>
#include <stdint.h>

#define B_ 4
#define S_ 1024
#define E_ 8
#define DE_ 128
#define SCALE_ 0.03125f   // 1/sqrt(1024)

typedef __attribute__((ext_vector_type(8))) short short8;
typedef __attribute__((ext_vector_type(4))) float f32x4;
typedef unsigned short ushort_t;
typedef unsigned int uint32;
typedef unsigned long long u64;
typedef unsigned char uchar;

__device__ __forceinline__ ushort_t f2bf(float f) {
    uint32 u = __float_as_uint(f);
    uint32 r = u + 0x7fffu + ((u >> 16) & 1u);
    return (ushort_t)(r >> 16);
}

// fp32 -> fp8 e4m3fn, RNE, saturating.
__device__ __forceinline__ uchar f2fp8(float f) {
    float a = fminf(fmaxf(f, -448.f), 448.f);
    uint32 u = __float_as_uint(a);
    uint32 s = (u >> 31) << 7;
    int ex = (int)((u >> 23) & 0xff);
    uint32 man = u & 0x7fffff;
    int e8 = ex - 127 + 7;
    if (e8 >= 1) {
        uint32 m = man >> 20;
        uint32 rem = man & 0xfffff;
        if (rem > 0x80000u || (rem == 0x80000u && (m & 1))) ++m;
        if (m == 8) { m = 0; ++e8; }
        if (e8 > 15) { e8 = 15; m = 6; }
        return (uchar)(s | ((uint32)e8 << 3) | m);
    } else {
        int m = (int)rintf(fabsf(a) * 512.f);
        if (m > 7) m = 7;
        return (uchar)(s | (uint32)m);
    }
}

// Async global->LDS DMA, 16B/lane. LDS dst = wave-uniform base + lane*16 (HW).
#define GLOAD_LDS16(g, l) __builtin_amdgcn_global_load_lds( \
    (const __attribute__((address_space(1))) unsigned int*)(g), \
    (__attribute__((address_space(3))) unsigned int*)(l), 16, 0, 0)

// fp8 frag read from a [rows][128B] swizzled tile: 8B of row, window kk*32+quad*8
__device__ __forceinline__ u64 fld8(const uchar* lds, int row, int kk, int quad) {
    int c = kk * 2 + (quad >> 1);
    int phys = c ^ (row & 7);
    return *(const u64*)(lds + row * 128 + (phys << 4) + ((quad & 1) << 3));
}

__device__ __forceinline__ void top2(const float* rp, int& i1, int& i2) {
    float v1 = rp[0]; i1 = 0;
    #pragma unroll
    for (int i = 1; i < 8; ++i) { float v = rp[i]; if (v > v1) { v1 = v; i1 = i; } }
    float v2 = -1e30f; i2 = 0;
    #pragma unroll
    for (int i = 0; i < 8; ++i) {
        if (i == i1) continue;
        float v = rp[i]; if (v > v2) { v2 = v; i2 = i; }
    }
}

// ---------------------------------------------------------------------------
// Kernel 1: prep (unchanged, ~13 us ≈ HBM floor).
// ---------------------------------------------------------------------------
__global__ __launch_bounds__(256) void prep_kernel(
        const float* __restrict__ Q, const float* __restrict__ K,
        const float* __restrict__ V, const float* __restrict__ route,
        const int* __restrict__ em,
        uchar* __restrict__ Qb, uchar* __restrict__ Kb,
        ushort_t* __restrict__ Vt, float* __restrict__ out) {
    __shared__ ushort_t tile[64][130];
    const int tid = threadIdx.x;
    const int sc = blockIdx.x, e = blockIdx.y, b = blockIdx.z;
    const int s0 = sc * 64;
    const size_t plane8 = ((size_t)(b * 8 + e)) << 17;

    const bool ak = em[e * B_ + b] != 0;
    int i1, i2; top2(route + b * 8, i1, i2);
    const bool av = (e == i1) || (e == i2);

    if (!av) {
        #pragma unroll
        for (int i = 0; i < 8; ++i) {
            int idx = tid + i * 256, r = idx >> 5, c4 = idx & 31;
            *(float4*)(out + (((size_t)(b * 1024 + s0 + r)) << 10) + (e << 7) + (c4 << 2))
                = make_float4(0.f, 0.f, 0.f, 0.f);
        }
    }
    if (ak) {
        #pragma unroll
        for (int i = 0; i < 2; ++i) {
            int u = tid + i * 256;
            int r = u >> 3, dg = u & 7;
            const float* qs = Q + ((size_t)(b * 1024 + s0 + r) << 10) + (e << 7) + (dg << 4);
            const float* ks = K + ((size_t)(b * 1024 + s0 + r) << 10) + (e << 7) + (dg << 4);
            union { uint4 w; uchar c[16]; } oq, ok;
            #pragma unroll
            for (int j = 0; j < 4; ++j) {
                float4 qv = ((const float4*)qs)[j];
                float4 kv = ((const float4*)ks)[j];
                oq.c[j*4+0] = f2fp8(qv.x); oq.c[j*4+1] = f2fp8(qv.y);
                oq.c[j*4+2] = f2fp8(qv.z); oq.c[j*4+3] = f2fp8(qv.w);
                ok.c[j*4+0] = f2fp8(kv.x); ok.c[j*4+1] = f2fp8(kv.y);
                ok.c[j*4+2] = f2fp8(kv.z); ok.c[j*4+3] = f2fp8(kv.w);
            }
            size_t oo = plane8 + ((size_t)(s0 + r) << 7) + (dg << 4);
            *(uint4*)(Qb + oo) = oq.w;
            *(uint4*)(Kb + oo) = ok.w;
        }
    }
    if (av) {
        #pragma unroll
        for (int i = 0; i < 8; ++i) {
            int idx = tid + i * 256, r = idx >> 5, c4 = idx & 31;
            size_t in_off = ((size_t)(b * 1024 + s0 + r) << 10) + (e << 7) + (c4 << 2);
            float4 v = *(const float4*)(V + in_off);
            ushort_t* p = &tile[r][c4 << 2];
            p[0] = f2bf(v.x); p[1] = f2bf(v.y); p[2] = f2bf(v.z); p[3] = f2bf(v.w);
        }
        __syncthreads();
        #pragma unroll
        for (int i = 0; i < 4; ++i) {
            int item = tid + i * 256, d = item & 127, sg = item >> 7;
            union { uint4 q; ushort_t u[8]; } tmp;
            #pragma unroll
            for (int j = 0; j < 8; ++j) tmp.u[j] = tile[sg * 8 + j][d];
            *(uint4*)(Vt + (((size_t)(b * 8 + e)) << 17) + (((size_t)d) << 10)
                      + s0 + (sg << 3)) = tmp.q;
        }
    }
}

// ---------------------------------------------------------------------------
// Kernel 2: attn_mega (R9 = R8 hardened): PER-WAVE DMA STREAMS.
// global_load_lds streams near fabric speed (R3) but the barrier-lockstep
// made one serial stream/CU; scalar loads have MLP~2 because the compiler
// register-minimizes (R4-R7). K/V use is WAVE-PRIVATE (wave w: K t-rows
// w*32..+31 per 256-group; V d-rows w*16..+15) => each wave runs its own
// rotating 3x4KB gload_lds pipeline with per-wave counted vmcnt, NO barriers.
// R9 hardening: Q staging is now WAVE-UNIFORM (all 8 slots staged by every
// wave, 2 loads/thread; slots >= ne unused) so the per-wave outstanding-VMEM
// count is identical on every wave — prologue 10, vmcnt(8) retires exactly
// the 2 Q loads. Fragments + accumulation order identical to R6 => absmax
// bit-identical (0.005859375). 512 thr, grid 256, XCD swizzle kept.
// ---------------------------------------------------------------------------
__global__ __launch_bounds__(512, 1) void attn_mega(
        const uchar* __restrict__ Qb, const uchar* __restrict__ Kb,
        const ushort_t* __restrict__ Vt, const float* __restrict__ route,
        const int* __restrict__ em, float* __restrict__ out) {

    __shared__ __align__(16) uchar kw[8 * 3 * 4096];   // per-wave rotating bufs (96K)
    __shared__ __align__(16) uchar qAll[16384];        // 8 Q tiles (2KB ea)
    __shared__ __align__(16) uchar attnL[32768];       // 16 x 1024 bf16, swizzled
    __shared__ float red[2][8][16];

    const int p = blockIdx.x;
    const int xcd = p & 7, b = xcd >> 1;
    const int stile = (p >> 3) + ((xcd & 1) << 5);
    const int s0 = stile * 16;
    const int tid = threadIdx.x;
    const int w = tid >> 6, lane = tid & 63;
    const int quad = lane >> 4, l16 = lane & 15;

    uint32 epack = 0; int ne = 0;
    #pragma unroll
    for (int e = 0; e < 8; ++e)
        if (em[e * B_ + b] != 0) { epack |= (uint32)e << (3 * ne); ++ne; }
    int i1, i2; top2(route + b * 8, i1, i2);

    const int tk = ne * 4;
    const int nc = tk + 16;
    uchar* mybuf = kw + w * 12288;          // wave-private 3 x 4KB

    // issue chunk g into buffer g%3 (4 gload_lds instructions per wave)
    auto issue = [&](int g) {
        uchar* dst = mybuf + (g % 3) * 4096;
        if (g < tk) {                        // K chunk: 32 rows x 128B
            int e = (epack >> (3 * (g >> 2))) & 7, c = g & 3;
            const uchar* src = Kb + (((size_t)(b * 8 + e)) << 17)
                               + (size_t)(c * 256 + w * 32) * 128;
            #pragma unroll
            for (int k2 = 0; k2 < 4; ++k2) {
                int u = lane + k2 * 64, r = u >> 3, cc = (u & 7) ^ (r & 7);
                GLOAD_LDS16(src + r * 128 + (cc << 4), dst + (u << 4));
            }
        } else {                             // V chunk: 16 rows x 256B (stride 2048)
            int v = g - tk;
            int eS = (v >> 3) ? i2 : i1, gg = v & 7;
            const uchar* src = (const uchar*)(Vt + (((size_t)(b * 8 + eS)) << 17))
                               + (size_t)(w * 16) * 2048 + gg * 256;
            #pragma unroll
            for (int k2 = 0; k2 < 4; ++k2) {
                int u = lane + k2 * 64, r = u >> 4, c = u & 15;
                int cc = (c & 8) | ((c & 7) ^ (r & 7));
                GLOAD_LDS16(src + (size_t)r * 2048 + (cc << 4), dst + (u << 4));
            }
        }
    };
    auto wait_for = [&](int g) {             // chunk g landed; keep g+1,g+2 in flight
        if (g + 2 < nc)      asm volatile("s_waitcnt vmcnt(8)" ::: "memory");
        else if (g + 1 < nc) asm volatile("s_waitcnt vmcnt(4)" ::: "memory");
        else                 asm volatile("s_waitcnt vmcnt(0)" ::: "memory");
    };

    // ---- prologue: WAVE-UNIFORM Q stage (all 8 slots), first 2 chunks ----
    #pragma unroll
    for (int k2 = 0; k2 < 2; ++k2) {
        int u2 = tid + k2 * 512;             // 0..1023 (8 slots x 128 units)
        int t = u2 >> 7, r = (u2 >> 3) & 15, c = u2 & 7;
        int e = (epack >> (3 * t)) & 7;      // t >= ne -> plane 0 (unused slot)
        int cc = c ^ (r & 7);
        GLOAD_LDS16(Qb + (((size_t)(b * 8 + e)) << 17) + (size_t)(s0 + r) * 128 + (cc << 4),
                    qAll + (u2 << 4));
    }
    issue(0); issue(1);
    asm volatile("s_waitcnt vmcnt(8)" ::: "memory");   // retire the 2 Q loads/wave
    __builtin_amdgcn_s_barrier();                       // Q visible block-wide
    __builtin_amdgcn_sched_barrier(0);

    f32x4 aacc[4][2];
    #pragma unroll
    for (int c = 0; c < 4; ++c)
        #pragma unroll
        for (int n = 0; n < 2; ++n) aacc[c][n] = (f32x4){0.f, 0.f, 0.f, 0.f};

    // ---- QK phase: per-wave chunk pipeline, one barrier per expert ----
    for (int i = 0; i < ne; ++i) {
        u64 af[4];
        #pragma unroll
        for (int kk = 0; kk < 4; ++kk)
            af[kk] = fld8(qAll + i * 2048, l16, kk, quad);

        float rsum[4] = {0.f, 0.f, 0.f, 0.f};
        f32x4 ps[4][2];
        #pragma unroll
        for (int c = 0; c < 4; ++c) {
            int g = i * 4 + c;
            if (g + 2 < nc) issue(g + 2);
            wait_for(g);
            const uchar* kb = mybuf + (g % 3) * 4096;
            #pragma unroll
            for (int n = 0; n < 2; ++n) {
                f32x4 s = {0.f, 0.f, 0.f, 0.f};
                #pragma unroll
                for (int kk = 0; kk < 4; ++kk) {
                    u64 bf = fld8(kb, n * 16 + l16, kk, quad);
                    s = __builtin_amdgcn_mfma_f32_16x16x32_fp8_fp8(
                        (long)af[kk], (long)bf, s, 0, 0, 0);
                }
                #pragma unroll
                for (int r = 0; r < 4; ++r) {
                    float p2 = __expf(s[r] * SCALE_);
                    ps[c][n][r] = p2;
                    rsum[r] += p2;
                }
            }
        }

        #pragma unroll
        for (int off = 1; off < 16; off <<= 1)
            #pragma unroll
            for (int r = 0; r < 4; ++r) rsum[r] += __shfl_xor(rsum[r], off, 64);
        if (l16 == 0) {
            #pragma unroll
            for (int r = 0; r < 4; ++r) red[i & 1][w][quad * 4 + r] = rsum[r];
        }
        asm volatile("s_waitcnt lgkmcnt(0)" ::: "memory");  // red writes drained
        __builtin_amdgcn_s_barrier();                        // DMA stays in flight
        __builtin_amdgcn_sched_barrier(0);
        float rinv[4];
        #pragma unroll
        for (int r = 0; r < 4; ++r) {
            float l = 0.f;
            #pragma unroll
            for (int ww = 0; ww < 8; ++ww) l += red[i & 1][ww][quad * 4 + r];
            rinv[r] = 1.0f / l;
        }
        #pragma unroll
        for (int c = 0; c < 4; ++c)
            #pragma unroll
            for (int n = 0; n < 2; ++n)
                #pragma unroll
                for (int r = 0; r < 4; ++r)
                    aacc[c][n][r] += ps[c][n][r] * rinv[r];
    }

    // ---- attn strip -> LDS bf16 (swizzled 16B chunks) ----
    #pragma unroll
    for (int c = 0; c < 4; ++c)
        #pragma unroll
        for (int n = 0; n < 2; ++n)
            #pragma unroll
            for (int r = 0; r < 4; ++r) {
                int row = quad * 4 + r;
                int t = c * 256 + w * 32 + n * 16 + l16;
                int ct = t >> 3;
                int phys = (ct & ~7) | ((ct & 7) ^ (row & 7));
                *(ushort_t*)(attnL + row * 2048 + (phys << 4) + ((t & 7) << 1)) =
                    f2bf(aacc[c][n][r]);
            }
    asm volatile("s_waitcnt lgkmcnt(0)" ::: "memory");
    __builtin_amdgcn_s_barrier();            // attnL visible; V DMA in flight
    __builtin_amdgcn_sched_barrier(0);

    // ---- PV: wave w owns d-rows w*16..+15; per-wave V chunk pipeline ----
    int selE[2] = {i1, i2};
    #pragma unroll
    for (int sel = 0; sel < 2; ++sel) {
        f32x4 oa = {0.f, 0.f, 0.f, 0.f};
        #pragma unroll
        for (int gg = 0; gg < 8; ++gg) {
            int g = tk + sel * 8 + gg;
            if (g + 2 < nc) issue(g + 2);
            wait_for(g);
            const uchar* vb = mybuf + (g % 3) * 4096;
            #pragma unroll
            for (int kk = 0; kk < 4; ++kk) {
                int tt = gg * 4 + kk;
                int ct = tt * 4 + quad;
                int phys = (ct & ~7) | ((ct & 7) ^ (l16 & 7));
                short8 afr = *(const short8*)(attnL + l16 * 2048 + (phys << 4));
                int cv = kk * 4 + quad;
                int pv2 = (cv & 8) | ((cv & 7) ^ (l16 & 7));
                short8 bfr = *(const short8*)(vb + l16 * 256 + (pv2 << 4));
                oa = __builtin_amdgcn_mfma_f32_16x16x32_bf16(afr, bfr, oa, 0, 0, 0);
            }
        }
        #pragma unroll
        for (int r = 0; r < 4; ++r)
            out[(((size_t)(b * 1024 + s0 + quad * 4 + r)) << 10)
                + selE[sel] * 128 + w * 16 + l16] = oa[r];
    }
}

// ---------------------------------------------------------------------------
extern "C" void kernel_launch(void* const* d_in, const int* in_sizes, int n_in,
                              void* d_out, int out_size, void* d_ws, size_t ws_size,
                              hipStream_t stream) {
    const float* Q     = (const float*)d_in[0];
    const float* K     = (const float*)d_in[1];
    const float* V     = (const float*)d_in[2];
    const float* route = (const float*)d_in[3];
    const int*   em    = (const int*)d_in[4];
    float* out = (float*)d_out;

    const size_t NB = (size_t)B_ * E_ * S_ * DE_;     // 4.19M elems
    uchar* Qb = (uchar*)d_ws;                         // fp8 planes
    uchar* Kb = Qb + NB;
    ushort_t* Vt = (ushort_t*)(Kb + NB);              // bf16 planes

    dim3 gp(16, 8, 4);
    prep_kernel<<<gp, 256, 0, stream>>>(Q, K, V, route, em, Qb, Kb, Vt, out);
    attn_mega<<<dim3(256), 512, 0, stream>>>(Qb, Kb, Vt, route, em, out);
}